// Round 1
// baseline (1020.337 us; speedup 1.0000x reference)
//
#include <hip/hip_runtime.h>

// InteractionNetwork (MeshGraphNets-style) fused MFMA implementation.
// Structure: per-64-row tile: gather/concat -> LDS (bf16), 3 chained
// mfma_f32_16x16x32_bf16 GEMMs with LDS-resident transposed weights,
// in-register LayerNorm + residual epilogue, atomicAdd segment-sum.

#define NNODES 50000
#define NEDGES 800000

typedef __bf16 bf16x8 __attribute__((ext_vector_type(8)));
typedef float f32x4 __attribute__((ext_vector_type(4)));

#define MFMA(a, b, c) __builtin_amdgcn_mfma_f32_16x16x32_bf16(a, b, c, 0, 0, 0)

// LDS layout (bytes). Weight rows padded +8 shorts so row stride = 4 mod 32
// dwords (breaks the row-major same-bank pattern on ds_read_b128).
#define OFF_W0 0        // [128][200] bf16  (50 KB)   W0^T rows=out(128), 192 used
#define OFF_W1 51200    // [128][136] bf16  (34 KB)   W1^T
#define OFF_W2 86016    // [64][136]  bf16  (17 KB)   W2^T
#define OFF_A 103424    // [64][200]  bf16  (25 KB)   concat input; reused as h1 [64][136]
#define OFF_H 129024    // [64][136]  bf16  (17 KB)   h0
#define OFF_E 146432    // [64][72]   bf16  (9 KB)    residual copy
#define SMEM_BYTES 155648

__device__ __forceinline__ unsigned short f2bf(float f) {
  unsigned u = __builtin_bit_cast(unsigned, f);
  u = (u + 0x7fffu + ((u >> 16) & 1u)) >> 16;  // RNE
  return (unsigned short)u;
}
__device__ __forceinline__ float bf2f(unsigned short h) {
  return __builtin_bit_cast(float, (unsigned)h << 16);
}

__device__ __forceinline__ void cvt8(const float* __restrict__ s, char* dA) {
  const float4 f0 = *(const float4*)s;
  const float4 f1 = *(const float4*)(s + 4);
  union { unsigned short us[8]; int4 v; } u;
  u.us[0] = f2bf(f0.x); u.us[1] = f2bf(f0.y); u.us[2] = f2bf(f0.z); u.us[3] = f2bf(f0.w);
  u.us[4] = f2bf(f1.x); u.us[5] = f2bf(f1.y); u.us[6] = f2bf(f1.z); u.us[7] = f2bf(f1.w);
  *(int4*)dA = u.v;
}
__device__ __forceinline__ void cvt8d(const float* __restrict__ s, char* dA, char* dE) {
  const float4 f0 = *(const float4*)s;
  const float4 f1 = *(const float4*)(s + 4);
  union { unsigned short us[8]; int4 v; } u;
  u.us[0] = f2bf(f0.x); u.us[1] = f2bf(f0.y); u.us[2] = f2bf(f0.z); u.us[3] = f2bf(f0.w);
  u.us[4] = f2bf(f1.x); u.us[5] = f2bf(f1.y); u.us[6] = f2bf(f1.z); u.us[7] = f2bf(f1.w);
  *(int4*)dA = u.v;
  *(int4*)dE = u.v;
}

// EDGE: concat = [x[dst] | x[src] | attr], residual = attr, atomicAdd into agg[dst].
// NODE: concat = [x | aggm | aggw],        residual = x,    no atomics, tail-masked.
template <bool EDGE>
__global__ __launch_bounds__(512, 1) void mlp_block(
    const float* __restrict__ xin, const int* __restrict__ srcI,
    const int* __restrict__ dstI, const float* __restrict__ attr,
    const float* __restrict__ aggm, const float* __restrict__ aggw,
    const unsigned short* __restrict__ Wt0, const unsigned short* __restrict__ Wt1,
    const unsigned short* __restrict__ Wt2, const float* __restrict__ b0,
    const float* __restrict__ b1, const float* __restrict__ b2,
    const float* __restrict__ gam, const float* __restrict__ bet,
    float* __restrict__ outp, float* __restrict__ agg, int M) {
  __shared__ __align__(16) char sm[SMEM_BYTES];
  const int tid = threadIdx.x;

  // ---- stage transposed bf16 weights into padded LDS (once per block) ----
  for (int i = tid; i < 128 * 24; i += 512) {  // W0t: 128 rows x 384B
    int r = i / 24, q = i - r * 24;
    *(int4*)(sm + OFF_W0 + r * 400 + q * 16) =
        *(const int4*)((const char*)Wt0 + r * 384 + q * 16);
  }
  for (int i = tid; i < 128 * 16; i += 512) {  // W1t: 128 x 256B
    int r = i >> 4, q = i & 15;
    *(int4*)(sm + OFF_W1 + r * 272 + q * 16) =
        *(const int4*)((const char*)Wt1 + r * 256 + q * 16);
  }
  for (int i = tid; i < 64 * 16; i += 512) {  // W2t: 64 x 256B
    int r = i >> 4, q = i & 15;
    *(int4*)(sm + OFF_W2 + r * 272 + q * 16) =
        *(const int4*)((const char*)Wt2 + r * 256 + q * 16);
  }
  __syncthreads();

  const int wave = tid >> 6, lane = tid & 63;
  const int lrow = lane & 15, lgrp = lane >> 4;
  const int srow = tid >> 3, ssub = tid & 7;  // staging: 8 threads/row, 8 cols each

  const int ntiles = (M + 63) >> 6;
  for (int t = blockIdx.x; t < ntiles; t += gridDim.x) {
    const int r0 = t << 6;
    // ---------------- stage concat (bf16) + residual copy ----------------
    {
      const int gr = r0 + srow;
      char* ap = sm + OFF_A + srow * 400 + ssub * 16;
      char* ep = sm + OFF_E + srow * 144 + ssub * 16;
      if (EDGE) {
        const int di = dstI[gr], si = srcI[gr];
        cvt8(xin + di * 64 + ssub * 8, ap);                 // x_i = x[dst]
        cvt8(xin + si * 64 + ssub * 8, ap + 128);           // x_j = x[src]
        cvt8d(attr + gr * 64 + ssub * 8, ap + 256, ep);     // edge_attr (+res)
      } else {
        if (gr < M) {
          cvt8d(xin + gr * 64 + ssub * 8, ap, ep);          // x (+res)
          cvt8(aggm + gr * 64 + ssub * 8, ap + 128);
          cvt8(aggw + gr * 64 + ssub * 8, ap + 256);
        } else {
          int4 z = {0, 0, 0, 0};
          *(int4*)ap = z; *(int4*)(ap + 128) = z; *(int4*)(ap + 256) = z;
          *(int4*)ep = z;
        }
      }
    }
    __syncthreads();
    // ---------------- L0: [64,192] @ W0 -> relu -> h0 [64,128] ----------------
    {
      const int mt = wave >> 1, nh = wave & 1;
      bf16x8 a[6];
      const char* ap = sm + OFF_A + (mt * 16 + lrow) * 400 + lgrp * 16;
#pragma unroll
      for (int kt = 0; kt < 6; ++kt) a[kt] = *(const bf16x8*)(ap + kt * 64);
#pragma unroll
      for (int ni = 0; ni < 4; ++ni) {
        const int nt = nh * 4 + ni, col = nt * 16 + lrow;
        const char* bp = sm + OFF_W0 + col * 400 + lgrp * 16;
        f32x4 c = {0.f, 0.f, 0.f, 0.f};
#pragma unroll
        for (int kt = 0; kt < 6; ++kt) c = MFMA(a[kt], *(const bf16x8*)(bp + kt * 64), c);
        const float bias = b0[col];
        unsigned short* hp = (unsigned short*)(sm + OFF_H) + (mt * 16 + lgrp * 4) * 136 + col;
#pragma unroll
        for (int r = 0; r < 4; ++r) hp[r * 136] = f2bf(fmaxf(c[r] + bias, 0.f));
      }
    }
    __syncthreads();
    // ---------------- L1: h0 @ W1 -> relu -> h1 [64,128] (into A region) ----------------
    {
      const int mt = wave >> 1, nh = wave & 1;
      bf16x8 a[4];
      const char* ap = sm + OFF_H + (mt * 16 + lrow) * 272 + lgrp * 16;
#pragma unroll
      for (int kt = 0; kt < 4; ++kt) a[kt] = *(const bf16x8*)(ap + kt * 64);
#pragma unroll
      for (int ni = 0; ni < 4; ++ni) {
        const int nt = nh * 4 + ni, col = nt * 16 + lrow;
        const char* bp = sm + OFF_W1 + col * 272 + lgrp * 16;
        f32x4 c = {0.f, 0.f, 0.f, 0.f};
#pragma unroll
        for (int kt = 0; kt < 4; ++kt) c = MFMA(a[kt], *(const bf16x8*)(bp + kt * 64), c);
        const float bias = b1[col];
        unsigned short* hp = (unsigned short*)(sm + OFF_A) + (mt * 16 + lgrp * 4) * 136 + col;
#pragma unroll
        for (int r = 0; r < 4; ++r) hp[r * 136] = f2bf(fmaxf(c[r] + bias, 0.f));
      }
    }
    __syncthreads();
    // ---------------- L2: h1 @ W2 + bias -> LayerNorm -> +res -> store (+atomic) ----------------
    if (wave < 4) {  // waves 0-3 own full 16-row x 64-col tiles => in-register LN
      const int mt = wave;
      bf16x8 a[4];
      const char* ap = sm + OFF_A + (mt * 16 + lrow) * 272 + lgrp * 16;
#pragma unroll
      for (int kt = 0; kt < 4; ++kt) a[kt] = *(const bf16x8*)(ap + kt * 64);
      f32x4 c[4];
#pragma unroll
      for (int nt = 0; nt < 4; ++nt) {
        const int col = nt * 16 + lrow;
        const char* bp = sm + OFF_W2 + col * 272 + lgrp * 16;
        f32x4 cc = {0.f, 0.f, 0.f, 0.f};
#pragma unroll
        for (int kt = 0; kt < 4; ++kt) cc = MFMA(a[kt], *(const bf16x8*)(bp + kt * 64), cc);
        const float bias = b2[col];
#pragma unroll
        for (int r = 0; r < 4; ++r) cc[r] += bias;
        c[nt] = cc;
      }
#pragma unroll
      for (int r = 0; r < 4; ++r) {
        float s = 0.f, ss = 0.f;
#pragma unroll
        for (int nt = 0; nt < 4; ++nt) { float v = c[nt][r]; s += v; ss += v * v; }
#pragma unroll
        for (int m = 1; m < 16; m <<= 1) {  // reduce across the 16-lane col group
          s += __shfl_xor(s, m, 64);
          ss += __shfl_xor(ss, m, 64);
        }
        const float mean = s * (1.f / 64.f);
        float var = ss * (1.f / 64.f) - mean * mean;
        var = fmaxf(var, 0.f);
        const float inv = rsqrtf(var + 1e-5f);
        const int lr = mt * 16 + lgrp * 4 + r;
        const int gr = r0 + lr;
        if (!EDGE && gr >= M) continue;  // node tail mask (stores only; shfl already done)
        int d = 0;
        if (EDGE) d = dstI[gr];
        const unsigned short* ep = (const unsigned short*)(sm + OFF_E) + lr * 72;
#pragma unroll
        for (int nt = 0; nt < 4; ++nt) {
          const int col = nt * 16 + lrow;
          const float v = (c[nt][r] - mean) * inv * gam[col] + bet[col] + bf2f(ep[col]);
          outp[gr * 64 + col] = v;
          if (EDGE) atomicAdd(agg + d * 64 + col, v);
        }
      }
    }
    __syncthreads();  // protect A/E regions before next tile's staging
  }
}

// ---- prep: transpose+cast all 9 weight matrices to bf16 [out][in] ----
struct PrepArgs { const float* w[9]; unsigned short* wt[3]; };

__global__ void prep_w(PrepArgs pa) {
  int i = blockIdx.x * 256 + threadIdx.x;
  if (i >= 3 * 49152) return;
  int mlp = i / 49152;
  int rem = i - mlp * 49152;
  int mat, off, K, N;
  if (rem < 24576)      { mat = 0; off = 0;     K = 192; N = 128; }
  else if (rem < 40960) { mat = 1; off = 24576; K = 128; N = 128; }
  else                  { mat = 2; off = 40960; K = 128; N = 64;  }
  int local = rem - off;
  int n = local / K, k = local - n * K;
  pa.wt[mlp][rem] = f2bf(pa.w[mlp * 3 + mat][k * N + n]);
}

__global__ void zero_f4(float4* p, int n) {
  int i = blockIdx.x * blockDim.x + threadIdx.x;
  if (i < n) p[i] = make_float4(0.f, 0.f, 0.f, 0.f);
}

extern "C" void kernel_launch(void* const* d_in, const int* in_sizes, int n_in,
                              void* d_out, int out_size, void* d_ws, size_t ws_size,
                              hipStream_t stream) {
  const float* x      = (const float*)d_in[0];
  const int*   meIdx  = (const int*)d_in[1];
  const float* meAttr = (const float*)d_in[2];
  const int*   weIdx  = (const int*)d_in[3];
  const float* weAttr = (const float*)d_in[4];

  float* out_x  = (float*)d_out;
  float* out_em = out_x + (size_t)NNODES * 64;
  float* out_ew = out_em + (size_t)NEDGES * 64;

  char* ws = (char*)d_ws;
  unsigned short* WtM = (unsigned short*)ws;             // 98304 B each
  unsigned short* WtW = (unsigned short*)(ws + 98304);
  unsigned short* WtU = (unsigned short*)(ws + 196608);
  float* aggm = (float*)(ws + 294912);
  float* aggw = aggm + (size_t)NNODES * 64;

  // zero agg buffers (atomics accumulate into them every call)
  zero_f4<<<dim3(6250), dim3(256), 0, stream>>>((float4*)aggm, 1600000);

  PrepArgs pa;
  for (int m = 0; m < 3; ++m)
    for (int l = 0; l < 3; ++l)
      pa.w[m * 3 + l] = (const float*)d_in[5 + m * 8 + l * 2];
  pa.wt[0] = WtM; pa.wt[1] = WtW; pa.wt[2] = WtU;
  prep_w<<<dim3(576), dim3(256), 0, stream>>>(pa);

  // mesh edge block: src=row0, dst=row1 of edge_index
  mlp_block<true><<<dim3(256), dim3(512), 0, stream>>>(
      x, meIdx, meIdx + NEDGES, meAttr, nullptr, nullptr,
      WtM, WtM + 24576, WtM + 40960,
      (const float*)d_in[6], (const float*)d_in[8], (const float*)d_in[10],
      (const float*)d_in[11], (const float*)d_in[12],
      out_em, aggm, NEDGES);
  // world edge block
  mlp_block<true><<<dim3(256), dim3(512), 0, stream>>>(
      x, weIdx, weIdx + NEDGES, weAttr, nullptr, nullptr,
      WtW, WtW + 24576, WtW + 40960,
      (const float*)d_in[14], (const float*)d_in[16], (const float*)d_in[18],
      (const float*)d_in[19], (const float*)d_in[20],
      out_ew, aggw, NEDGES);
  // node update block
  mlp_block<false><<<dim3(256), dim3(512), 0, stream>>>(
      x, nullptr, nullptr, nullptr, aggm, aggw,
      WtU, WtU + 24576, WtU + 40960,
      (const float*)d_in[22], (const float*)d_in[24], (const float*)d_in[26],
      (const float*)d_in[27], (const float*)d_in[28],
      out_x, nullptr, NNODES);
}